// Round 8
// baseline (1620.962 us; speedup 1.0000x reference)
//
#include <hip/hip_runtime.h>
#include <math.h>

#define DEV_INLINE __device__ __forceinline__

typedef __attribute__((ext_vector_type(8))) short short8_t;
typedef __attribute__((ext_vector_type(4))) float f32x4;

// TF32 rounding: RNE to 10-bit mantissa (kept for conv1 + fc2/fc3).
DEV_INLINE float tf32r(float x) {
  unsigned int u = __float_as_uint(x);
  unsigned int r = u + 0xFFFu + ((u >> 13) & 1u);
  r &= 0xFFFFE000u;
  return __uint_as_float(r);
}

// bf16 RNE helpers for split-precision MFMA path.
DEV_INLINE unsigned short bf16_hi(float x) {
  unsigned int u = __float_as_uint(x);
  return (unsigned short)((u + 0x7FFFu + ((u >> 16) & 1u)) >> 16);
}
DEV_INLINE float bf16_f(unsigned short h) {
  return __uint_as_float((unsigned int)h << 16);
}

// ---------------------------------------------------------------------------
// Quantization in f64: xd = clip(x*std + mean, 0, 1); q = trunc(xd*255)
// ---------------------------------------------------------------------------
DEV_INLINE int quantize_px(float v, double s, double m) {
  double xd = __dadd_rn(__dmul_rn((double)v, s), m);
  xd = fmin(fmax(xd, 0.0), 1.0);
  return (int)__dmul_rn(xd, 255.0);
}

// ---------------------------------------------------------------------------
// Co-occurrence, LDS-privatized histograms (no global atomics).
// ---------------------------------------------------------------------------
__global__ __launch_bounds__(256, 2) void co_hist(const float* __restrict__ x,
                                                  unsigned int* __restrict__ hcopy) {
  __shared__ unsigned int hist[16384];        // 32768 u16 bins (one half-range)
  __shared__ unsigned short qrow[2][257];
  const int t = threadIdx.x;
  const int bc = blockIdx.x;                  // b*3 + c
  const int r = blockIdx.y;                   // row chunk 0..3
  const int half = blockIdx.z;                // bin-range half (bit15)
  const int c = bc % 3;
  const double S = (c == 0) ? (double)0.229f : (c == 1) ? (double)0.224f : (double)0.225f;
  const double M = (c == 0) ? (double)0.485f : (c == 1) ? (double)0.456f : (double)0.406f;
  const float* p = x + (size_t)bc * 65536;

  for (int i = t; i < 16384; i += 256) hist[i] = 0u;

  const int y0 = r * 64;
  qrow[y0 & 1][t] = (unsigned short)quantize_px(p[y0 * 256 + t], S, M);
  __syncthreads();

  const bool xr = t < 255;
  for (int y = y0; y < y0 + 64; ++y) {
    const int cur = y & 1, nxt = cur ^ 1;
    const bool yd = (y + 1) < 256;
    if (yd) qrow[nxt][t] = (unsigned short)quantize_px(p[(y + 1) * 256 + t], S, M);
    __syncthreads();
    const int q00 = qrow[cur][t];
    const int q01 = xr ? (int)qrow[cur][t + 1] : 0;
    if (xr) {
      int b0 = q00 * 256 + q01;
      if ((b0 >> 15) == half)
        atomicAdd(&hist[(b0 >> 1) & 16383], 1u << ((b0 & 1) * 16));
    }
    if (yd) {
      const int q10 = qrow[nxt][t];
      int b1 = q00 * 256 + q10;
      if ((b1 >> 15) == half)
        atomicAdd(&hist[(b1 >> 1) & 16383], 1u << ((b1 & 1) * 16));
      if (xr) {
        const int q11 = qrow[nxt][t + 1];
        int b2 = q00 * 256 + q11;
        int b3 = q01 * 256 + q10;
        if ((b2 >> 15) == half)
          atomicAdd(&hist[(b2 >> 1) & 16383], 1u << ((b2 & 1) * 16));
        if ((b3 >> 15) == half)
          atomicAdd(&hist[(b3 >> 1) & 16383], 1u << ((b3 & 1) * 16));
      }
    }
    __syncthreads();
  }

  unsigned int* outp = hcopy + ((size_t)r * 48 + bc) * 32768 + half * 16384;
  for (int i = t; i < 16384; i += 256) outp[i] = hist[i];
}

__global__ __launch_bounds__(256) void co_reduce(const unsigned int* __restrict__ hcopy,
                                                 float* __restrict__ co) {
  int i = blockIdx.x * 256 + threadIdx.x;     // 48*32768 words
  int bc = i >> 15, w = i & 32767;
  unsigned int lo = 0, hi = 0;
#pragma unroll
  for (int r = 0; r < 4; ++r) {
    unsigned int v = hcopy[((size_t)r * 48 + bc) * 32768 + w];
    lo += v & 0xFFFFu;
    hi += v >> 16;
  }
  float2 o;
  o.x = (float)lo;
  o.y = (float)hi;
  *(float2*)&co[(size_t)bc * 65536 + w * 2] = o;
}

// ---------------------------------------------------------------------------
// VALU conv (kept ONLY for conv1, CIN=3 — too narrow for K=32 MFMA).
// ---------------------------------------------------------------------------
template <int K, int CIN, int COUT, int H, int W, bool RELU, bool POOL>
__global__ __launch_bounds__(256, 2) void conv_fast(
    const float* __restrict__ in, const float* __restrict__ wgt,
    const float* __restrict__ bias, float* __restrict__ out) {
  constexpr int TH = 16, TW = 16, CO_BLK = 16;
  constexpr int CI_BLK = (CIN % 8 == 0) ? 8 : CIN;
  constexpr int PAD = K / 2;
  constexpr int IR = TH + K - 1, IC = TW + K - 1, ICP = IC + 1;
  constexpr int TILES_X = W / TW;

  __shared__ float s_in[CI_BLK][IR][ICP];
  __shared__ float s_w[CO_BLK][CI_BLK][K * K];

  const int t = threadIdx.x;
  const int by = blockIdx.x / TILES_X, bx = blockIdx.x % TILES_X;
  const int co_base = blockIdx.y * CO_BLK;
  const int b = blockIdx.z;

  const int cog = t >> 6;
  const int pg = t & 63;
  const int py0 = (pg >> 3) * 2;
  const int px0 = (pg & 7) * 2;

  float acc[2][2][4];
#pragma unroll
  for (int i = 0; i < 2; ++i)
#pragma unroll
    for (int j = 0; j < 2; ++j)
#pragma unroll
      for (int k = 0; k < 4; ++k) acc[i][j][k] = 0.f;

  const int y0g = by * TH - PAD, x0g = bx * TW - PAD;
  const float* inb = in + (size_t)b * CIN * H * W;

  for (int ci0 = 0; ci0 < CIN; ci0 += CI_BLK) {
    for (int i = t; i < CI_BLK * IR * IC; i += 256) {
      int ci = i / (IR * IC), rem = i % (IR * IC);
      int rr = rem / IC, cc = rem % IC;
      int gy = y0g + rr, gx = x0g + cc;
      float v = 0.f;
      if (gy >= 0 && gy < H && gx >= 0 && gx < W)
        v = tf32r(inb[(size_t)(ci0 + ci) * H * W + gy * W + gx]);
      s_in[ci][rr][cc] = v;
    }
    for (int i = t; i < CO_BLK * CI_BLK * K * K; i += 256) {
      int co = i / (CI_BLK * K * K), rem = i % (CI_BLK * K * K);
      int ci = rem / (K * K), kk = rem % (K * K);
      s_w[co][ci][kk] =
          tf32r(wgt[((size_t)(co_base + co) * CIN + (ci0 + ci)) * K * K + kk]);
    }
    __syncthreads();

#pragma unroll 1
    for (int ci = 0; ci < CI_BLK; ++ci) {
#pragma unroll
      for (int ky = 0; ky < K; ++ky) {
        float wr[4][K];
#pragma unroll
        for (int co = 0; co < 4; ++co)
#pragma unroll
          for (int kx = 0; kx < K; ++kx)
            wr[co][kx] = s_w[cog * 4 + co][ci][ky * K + kx];
#pragma unroll
        for (int py = 0; py < 2; ++py) {
          float r[K + 1];
#pragma unroll
          for (int j = 0; j < K + 1; ++j)
            r[j] = s_in[ci][py0 + py + ky][px0 + j];
#pragma unroll
          for (int kx = 0; kx < K; ++kx)
#pragma unroll
            for (int px = 0; px < 2; ++px)
#pragma unroll
              for (int co = 0; co < 4; ++co)
                acc[py][px][co] = fmaf(r[px + kx], wr[co][kx], acc[py][px][co]);
        }
      }
    }
    __syncthreads();
  }

  if (POOL) {
    constexpr int HO = H / 2, WO = W / 2;
    int oy = by * (TH / 2) + (pg >> 3), ox = bx * (TW / 2) + (pg & 7);
#pragma unroll
    for (int co = 0; co < 4; ++co) {
      int cg = co_base + cog * 4 + co;
      float v = fmaxf(fmaxf(acc[0][0][co], acc[0][1][co]),
                      fmaxf(acc[1][0][co], acc[1][1][co]));
      v += bias[cg];
      out[((size_t)b * COUT + cg) * HO * WO + oy * WO + ox] = v;
    }
  } else {
#pragma unroll
    for (int co = 0; co < 4; ++co) {
      int cg = co_base + cog * 4 + co;
      float bv = bias[cg];
#pragma unroll
      for (int py = 0; py < 2; ++py) {
        float2 v;
        v.x = acc[py][0][co] + bv;
        v.y = acc[py][1][co] + bv;
        if (RELU) { v.x = fmaxf(v.x, 0.f); v.y = fmaxf(v.y, 0.f); }
        *(float2*)&out[((size_t)b * COUT + cg) * H * W +
                       (by * TH + py0 + py) * W + (bx * TW + px0)] = v;
      }
    }
  }
}

// ---------------------------------------------------------------------------
// Weight pre-transform: f32 [CO][CI][K*K] -> bf16 hi/lo [tap][CO][CI].
// ---------------------------------------------------------------------------
__global__ void wprep(const float* __restrict__ w, unsigned short* __restrict__ whi,
                      unsigned short* __restrict__ wlo, int CO, int CI, int KK) {
  int i = blockIdx.x * 256 + threadIdx.x;
  if (i >= KK * CO * CI) return;
  int ci = i % CI;
  int rem = i / CI;
  int co = rem % CO;
  int tap = rem / CO;
  float v = w[((size_t)co * CI + ci) * KK + tap];
  unsigned short h = bf16_hi(v);
  whi[i] = h;
  wlo[i] = bf16_hi(v - bf16_f(h));
}

// ---------------------------------------------------------------------------
// MFMA conv (conv2..conv6): tap-decomposed implicit GEMM, split-bf16 f32
// emulation (acc += ahi*bhi + ahi*blo + alo*bhi; fp32 accumulate).
// R7 post-mortem: two-pass hi/lo staging REORDERED the fp32 accumulation
// (absmax 3.81e-6 -> 4.77e-6, over the 4.67e-6 threshold). Reverted to the
// R6 single-pass body (bit-identical outputs to R6). Occupancy is instead
// raised by tile GEOMETRY (order-preserving):
//   conv2: WC=1,WR=4,XS=1 -> RIN*XIN=12*20, LDS 38400 B -> 4 blocks/CU,
//          and -17% staging volume.
//   conv4/6: WC=2,WR=2,XS=1 -> LDS 25600 B -> 6 blocks/CU (VGPR-bound).
// ---------------------------------------------------------------------------
template <int K, int CIN, int COUT, int H, int W, int WC, int WR, int XS, bool POOL>
__global__ __launch_bounds__(256, 4) void conv_mfma(
    const float* __restrict__ in, const unsigned short* __restrict__ whi,
    const unsigned short* __restrict__ wlo, const float* __restrict__ bias,
    float* __restrict__ out) {
  constexpr int XW = 4 / (WC * WR);
  static_assert(WC * WR * XW == 4, "wave decomposition");
  constexpr int RW = POOL ? 2 : 1;     // rows per wave
  constexpr int RB = WR * RW;          // rows per block
  constexpr int P = RW * XS;
  constexpr int PAD = K / 2;
  constexpr int BX = 16 * XS * XW;
  constexpr int RIN = RB + K - 1;
  constexpr int XIN = BX + K - 1;
  constexpr int CIP = 40;              // 32 ci + 8 pad -> 80B px stride
  constexpr int XT = W / BX;
  static_assert(CIN % 32 == 0, "ci blocking");
  static_assert(W % BX == 0, "x tiling");
  static_assert(H % RB == 0, "y tiling");

  __shared__ __align__(16) unsigned short s_hi[RIN][XIN][CIP];
  __shared__ __align__(16) unsigned short s_lo[RIN][XIN][CIP];

  const int t = threadIdx.x;
  const int l = t & 63, l15 = l & 15, cig = l >> 4;
  const int wv = t >> 6;
  const int wc = wv / (WR * XW);
  const int wrm = wv % (WR * XW);
  const int wr = wrm / XW, wx = wrm % XW;
  const int tx = blockIdx.x % XT, ty = blockIdx.x / XT;
  const int x0 = tx * BX, y0 = ty * RB;
  const int xloc = wx * 16 * XS;
  const int yloc = wr * RW;
  const int cb = blockIdx.y * (32 * WC) + wc * 32;
  const int b = blockIdx.z;

  f32x4 acc[2][P];
#pragma unroll
  for (int f = 0; f < 2; ++f)
#pragma unroll
    for (int p = 0; p < P; ++p)
#pragma unroll
      for (int k = 0; k < 4; ++k) acc[f][p][k] = 0.f;

  const float* inb = in + (size_t)b * CIN * H * W;

#pragma unroll 1
  for (int ci0 = 0; ci0 < CIN; ci0 += 32) {
    // ---- stage 32 ci of halo'd input, f32 -> bf16 hi/lo ----
    constexpr int NIT = RIN * XIN * 8;   // 8 groups of 4 ci
    const float* cbase = inb + (size_t)ci0 * H * W;
    for (int i = t; i < NIT; i += 256) {
      int xx = i % XIN;
      int rem = i / XIN;
      int c4 = (rem & 7) * 4;
      int r = rem >> 3;
      int gy = y0 + r - PAD, gx = x0 + xx - PAD;
      float v0 = 0.f, v1 = 0.f, v2 = 0.f, v3 = 0.f;
      if (gy >= 0 && gy < H && gx >= 0 && gx < W) {
        const float* p = cbase + ((size_t)c4 * H + gy) * W + gx;
        v0 = p[0];
        v1 = p[(size_t)H * W];
        v2 = p[2 * (size_t)H * W];
        v3 = p[3 * (size_t)H * W];
      }
      unsigned short h0 = bf16_hi(v0), h1 = bf16_hi(v1);
      unsigned short h2 = bf16_hi(v2), h3 = bf16_hi(v3);
      unsigned short e0 = bf16_hi(v0 - bf16_f(h0)), e1 = bf16_hi(v1 - bf16_f(h1));
      unsigned short e2 = bf16_hi(v2 - bf16_f(h2)), e3 = bf16_hi(v3 - bf16_f(h3));
      uint2 ph, pl;
      ph.x = (unsigned)h0 | ((unsigned)h1 << 16);
      ph.y = (unsigned)h2 | ((unsigned)h3 << 16);
      pl.x = (unsigned)e0 | ((unsigned)e1 << 16);
      pl.y = (unsigned)e2 | ((unsigned)e3 << 16);
      *(uint2*)&s_hi[r][xx][c4] = ph;
      *(uint2*)&s_lo[r][xx][c4] = pl;
    }
    __syncthreads();

#pragma unroll
    for (int ky = 0; ky < K; ++ky) {
#pragma unroll
      for (int kx = 0; kx < K; ++kx) {
        const int tap = ky * K + kx;
        short8_t ah[2], al[2];
#pragma unroll
        for (int f = 0; f < 2; ++f) {
          int off = (tap * COUT + cb + f * 16 + l15) * CIN + ci0 + cig * 8;
          ah[f] = *(const short8_t*)(whi + off);
          al[f] = *(const short8_t*)(wlo + off);
        }
#pragma unroll
        for (int fr = 0; fr < RW; ++fr) {
#pragma unroll
          for (int fx = 0; fx < XS; ++fx) {
            const int pf = fr * XS + fx;
            const int xr = xloc + fx * 16 + kx + l15;
            short8_t bh = *(const short8_t*)&s_hi[yloc + fr + ky][xr][cig * 8];
            short8_t bl = *(const short8_t*)&s_lo[yloc + fr + ky][xr][cig * 8];
#pragma unroll
            for (int f = 0; f < 2; ++f) {
              acc[f][pf] = __builtin_amdgcn_mfma_f32_16x16x32_bf16(
                  ah[f], bh, acc[f][pf], 0, 0, 0);
              acc[f][pf] = __builtin_amdgcn_mfma_f32_16x16x32_bf16(
                  ah[f], bl, acc[f][pf], 0, 0, 0);
              acc[f][pf] = __builtin_amdgcn_mfma_f32_16x16x32_bf16(
                  al[f], bh, acc[f][pf], 0, 0, 0);
            }
          }
        }
      }
    }
    __syncthreads();
  }

  // ---- epilogue: D lane map col(px)=l&15, row(co)=cig*4+r ----
  if (POOL) {
    constexpr int HO = H / 2, WO = W / 2;
    const int oy = (y0 + yloc) >> 1;
#pragma unroll
    for (int f = 0; f < 2; ++f)
#pragma unroll
      for (int fx = 0; fx < XS; ++fx)
#pragma unroll
        for (int r = 0; r < 4; ++r) {
          float m = fmaxf(acc[f][fx][r], acc[f][XS + fx][r]);  // row pair
          float mm = fmaxf(m, __shfl_xor(m, 1));               // x pair
          if ((l15 & 1) == 0) {
            int co = cb + f * 16 + cig * 4 + r;
            int ox = (x0 + xloc + fx * 16 + l15) >> 1;
            out[((size_t)(b * COUT + co) * HO + oy) * WO + ox] = mm + bias[co];
          }
        }
  } else {
#pragma unroll
    for (int f = 0; f < 2; ++f)
#pragma unroll
      for (int fx = 0; fx < XS; ++fx)
#pragma unroll
        for (int r = 0; r < 4; ++r) {
          int co = cb + f * 16 + cig * 4 + r;
          float v = fmaxf(acc[f][fx][r] + bias[co], 0.f);      // relu layers
          out[((size_t)(b * COUT + co) * H + y0 + yloc) * W +
              x0 + xloc + fx * 16 + l15] = v;
        }
  }
}

// ---------------------------------------------------------------------------
// FC1 as split-bf16 MFMA GEMM: [16 b x 131072] x [131072 x 256 o].
// ---------------------------------------------------------------------------
__global__ __launch_bounds__(256) void hprep(const float* __restrict__ h,
                                             unsigned short* __restrict__ hhi,
                                             unsigned short* __restrict__ hlo) {
  int i = blockIdx.x * 256 + threadIdx.x;     // 2,097,152 elements
  float v = h[i];
  unsigned short hi = bf16_hi(v);
  hhi[i] = hi;
  hlo[i] = bf16_hi(v - bf16_f(hi));
}

__global__ __launch_bounds__(256) void fc1_mfma(const float* __restrict__ w,
                                                const unsigned short* __restrict__ hhi,
                                                const unsigned short* __restrict__ hlo,
                                                float* __restrict__ partial) {
  const int t = threadIdx.x;
  const int l15 = t & 15, cig = (t >> 4) & 3, wv = t >> 6;
  const int o0 = blockIdx.x * 16;
  const int slot = blockIdx.y * 4 + wv;       // 0..255
  const int kbase = slot * 512 + cig * 8;
  const float* wrow = w + (size_t)(o0 + l15) * 131072;
  const unsigned short* hh = hhi + (size_t)l15 * 131072;
  const unsigned short* hl = hlo + (size_t)l15 * 131072;
  f32x4 acc = {0.f, 0.f, 0.f, 0.f};
#pragma unroll 4
  for (int ks = 0; ks < 16; ++ks) {
    const int k = kbase + ks * 32;
    float4 w0 = *(const float4*)(wrow + k);
    float4 w1 = *(const float4*)(wrow + k + 4);
    float wf[8] = {w0.x, w0.y, w0.z, w0.w, w1.x, w1.y, w1.z, w1.w};
    short8_t ah, al;
#pragma unroll
    for (int j = 0; j < 8; ++j) {
      unsigned short h_ = bf16_hi(wf[j]);
      ah[j] = (short)h_;
      al[j] = (short)bf16_hi(wf[j] - bf16_f(h_));
    }
    short8_t bh = *(const short8_t*)(hh + k);
    short8_t bl = *(const short8_t*)(hl + k);
    acc = __builtin_amdgcn_mfma_f32_16x16x32_bf16(ah, bh, acc, 0, 0, 0);
    acc = __builtin_amdgcn_mfma_f32_16x16x32_bf16(ah, bl, acc, 0, 0, 0);
    acc = __builtin_amdgcn_mfma_f32_16x16x32_bf16(al, bh, acc, 0, 0, 0);
  }
  // D: col = l15 = batch, row = cig*4+r = o offset. Layout [slot][b][o].
  float* pr = partial + ((size_t)slot * 16 + l15) * 256 + o0 + cig * 4;
#pragma unroll
  for (int r = 0; r < 4; ++r) pr[r] = acc[r];
}

__global__ __launch_bounds__(256) void fc1_reduce(const float* __restrict__ partial,
                                                  const float* __restrict__ fb1,
                                                  float* __restrict__ f1) {
  const int b = blockIdx.x, o = threadIdx.x;  // 16 x 256
  float s = 0.f;
#pragma unroll 8
  for (int sl = 0; sl < 256; ++sl) s += partial[((size_t)sl * 16 + b) * 256 + o];
  f1[b * 256 + o] = fmaxf(s + fb1[o], 0.f);
}

__global__ void fc2_kernel(const float* __restrict__ f1,
                           const float* __restrict__ w,
                           const float* __restrict__ fb2,
                           float* __restrict__ f2) {
  int bb = blockIdx.x, o = threadIdx.x;
  __shared__ float s[256];
  s[o] = tf32r(f1[bb * 256 + o]);
  __syncthreads();
  const float* wr = w + (size_t)o * 256;
  float acc = 0.f;
#pragma unroll 8
  for (int k = 0; k < 256; ++k) acc = fmaf(tf32r(wr[k]), s[k], acc);
  f2[bb * 256 + o] = fmaxf(acc + fb2[o], 0.f);
}

__global__ void fc3_kernel(const float* __restrict__ f2,
                           const float* __restrict__ w,
                           const float* __restrict__ fb3,
                           float* __restrict__ out) {
  int bb = blockIdx.x, t = threadIdx.x;  // 64 threads = 1 wave
  float p = 0.f;
#pragma unroll
  for (int k = t; k < 256; k += 64)
    p = fmaf(tf32r(w[k]), tf32r(f2[bb * 256 + k]), p);
#pragma unroll
  for (int off = 32; off; off >>= 1) p += __shfl_down(p, off);
  if (t == 0) {
    double z = (double)p + (double)fb3[0];
    out[bb] = (float)(1.0 / (1.0 + exp(-z)));
  }
}

// ---------------------------------------------------------------------------
extern "C" void kernel_launch(void* const* d_in, const int* in_sizes, int n_in,
                              void* d_out, int out_size, void* d_ws,
                              size_t ws_size, hipStream_t stream) {
  const float* x   = (const float*)d_in[0];
  const float* w1  = (const float*)d_in[1];  const float* b1  = (const float*)d_in[2];
  const float* w2  = (const float*)d_in[3];  const float* b2  = (const float*)d_in[4];
  const float* w3  = (const float*)d_in[5];  const float* b3  = (const float*)d_in[6];
  const float* w4  = (const float*)d_in[7];  const float* b4  = (const float*)d_in[8];
  const float* w5  = (const float*)d_in[9];  const float* b5  = (const float*)d_in[10];
  const float* w6  = (const float*)d_in[11]; const float* b6  = (const float*)d_in[12];
  const float* fw1 = (const float*)d_in[13]; const float* fb1 = (const float*)d_in[14];
  const float* fw2 = (const float*)d_in[15]; const float* fb2 = (const float*)d_in[16];
  const float* fw3 = (const float*)d_in[17]; const float* fb3 = (const float*)d_in[18];
  float* outp = (float*)d_out;

  float* big    = (float*)d_ws;                // 33,554,432 floats (134 MB)
  float* small  = big + 33554432;              //  8,388,608 floats (33.5 MB)
  float* f1     = small + 8388608;             //  4096
  float* f2     = f1 + 4096;                   //  4096
  // bf16 hi/lo weight arrays for conv2..6 (2.52 MB total), [tap][co][ci]
  unsigned short* w2h = (unsigned short*)(f2 + 4096);
  unsigned short* w2l = w2h + 25600;           // 25*32*32
  unsigned short* w3h = w2l + 25600;
  unsigned short* w3l = w3h + 18432;           // 9*64*32
  unsigned short* w4h = w3l + 18432;
  unsigned short* w4l = w4h + 102400;          // 25*64*64
  unsigned short* w5h = w4l + 102400;
  unsigned short* w5l = w5h + 73728;           // 9*128*64
  unsigned short* w6h = w5l + 73728;
  unsigned short* w6l = w6h + 409600;          // 25*128*128

  // fc1 scratch lives in `big` (free once conv6 has consumed conv5's output)
  unsigned short* hhi = (unsigned short*)big;        // 2,097,152 u16 = 4 MB
  unsigned short* hlo = hhi + 2097152;               // 4 MB
  float* partial = (float*)(hlo + 2097152);          // 256*16*256 f32 = 4 MB

  // weight pre-transform (tiny)
  wprep<<<(25600 + 255) / 256, 256, 0, stream>>>(w2, w2h, w2l, 32, 32, 25);
  wprep<<<(18432 + 255) / 256, 256, 0, stream>>>(w3, w3h, w3l, 64, 32, 9);
  wprep<<<(102400 + 255) / 256, 256, 0, stream>>>(w4, w4h, w4l, 64, 64, 25);
  wprep<<<(73728 + 255) / 256, 256, 0, stream>>>(w5, w5h, w5l, 128, 64, 9);
  wprep<<<(409600 + 255) / 256, 256, 0, stream>>>(w6, w6h, w6l, 128, 128, 25);

  // co-occurrence: LDS-private histograms -> 4 packed copies (in `big`) ->
  // reduce into `small`.
  unsigned int* hcopy = (unsigned int*)big;    // 4*48*32768 u32 = 25.2 MB
  co_hist<<<dim3(48, 4, 2), 256, 0, stream>>>(x, hcopy);
  co_reduce<<<6144, 256, 0, stream>>>(hcopy, small);

  // conv1: VALU path (CIN=3)
  conv_fast<3, 3, 32, 256, 256, true, false>
      <<<dim3(256, 2, 16), 256, 0, stream>>>(small, w1, b1, big);

  // conv2..6: MFMA split-bf16 path (R6 body; smaller tiles for occupancy)
  conv_mfma<5, 32, 32, 256, 256, 1, 4, 1, true>      // LDS 38400, 4 blk/CU
      <<<dim3(16 * 32, 1, 16), 256, 0, stream>>>(big, w2h, w2l, b2, small);
  conv_mfma<3, 32, 64, 128, 128, 2, 1, 2, false>     // unchanged (31680)
      <<<dim3(2 * 128, 1, 16), 256, 0, stream>>>(small, w3h, w3l, b3, big);
  conv_mfma<5, 64, 64, 128, 128, 2, 2, 1, true>      // LDS 25600, 6 blk/CU
      <<<dim3(8 * 32, 1, 16), 256, 0, stream>>>(big, w4h, w4l, b4, small);
  conv_mfma<3, 64, 128, 64, 64, 2, 1, 2, false>      // unchanged
      <<<dim3(1 * 64, 2, 16), 256, 0, stream>>>(small, w5h, w5l, b5, big);
  conv_mfma<5, 128, 128, 64, 64, 2, 2, 1, true>      // LDS 25600, 6 blk/CU
      <<<dim3(4 * 16, 2, 16), 256, 0, stream>>>(big, w6h, w6l, b6, small);

  // fc head: fc1 via MFMA (weights read exactly once), fc2/fc3 tiny
  hprep<<<8192, 256, 0, stream>>>(small, hhi, hlo);
  fc1_mfma<<<dim3(16, 64), 256, 0, stream>>>(fw1, hhi, hlo, partial);
  fc1_reduce<<<16, 256, 0, stream>>>(partial, fb1, f1);
  fc2_kernel<<<16, 256, 0, stream>>>(f1, fw2, fb2, f2);
  fc3_kernel<<<16, 64, 0, stream>>>(f2, fw3, fb3, outp);
}

// Round 9
// 1236.744 us; speedup vs baseline: 1.3107x; 1.3107x over previous
//
#include <hip/hip_runtime.h>
#include <math.h>

#define DEV_INLINE __device__ __forceinline__

typedef __attribute__((ext_vector_type(8))) short short8_t;
typedef __attribute__((ext_vector_type(4))) float f32x4;

// TF32 rounding: RNE to 10-bit mantissa (kept for conv1 + fc2/fc3).
DEV_INLINE float tf32r(float x) {
  unsigned int u = __float_as_uint(x);
  unsigned int r = u + 0xFFFu + ((u >> 13) & 1u);
  r &= 0xFFFFE000u;
  return __uint_as_float(r);
}

// bf16 RNE helpers for split-precision MFMA path.
DEV_INLINE unsigned short bf16_hi(float x) {
  unsigned int u = __float_as_uint(x);
  return (unsigned short)((u + 0x7FFFu + ((u >> 16) & 1u)) >> 16);
}
DEV_INLINE float bf16_f(unsigned short h) {
  return __uint_as_float((unsigned int)h << 16);
}

// ---------------------------------------------------------------------------
// Quantization in f64: xd = clip(x*std + mean, 0, 1); q = trunc(xd*255)
// ---------------------------------------------------------------------------
DEV_INLINE int quantize_px(float v, double s, double m) {
  double xd = __dadd_rn(__dmul_rn((double)v, s), m);
  xd = fmin(fmax(xd, 0.0), 1.0);
  return (int)__dmul_rn(xd, 255.0);
}

// ---------------------------------------------------------------------------
// Co-occurrence, LDS-privatized histograms (no global atomics).
// ---------------------------------------------------------------------------
__global__ __launch_bounds__(256, 2) void co_hist(const float* __restrict__ x,
                                                  unsigned int* __restrict__ hcopy) {
  __shared__ unsigned int hist[16384];        // 32768 u16 bins (one half-range)
  __shared__ unsigned short qrow[2][257];
  const int t = threadIdx.x;
  const int bc = blockIdx.x;                  // b*3 + c
  const int r = blockIdx.y;                   // row chunk 0..3
  const int half = blockIdx.z;                // bin-range half (bit15)
  const int c = bc % 3;
  const double S = (c == 0) ? (double)0.229f : (c == 1) ? (double)0.224f : (double)0.225f;
  const double M = (c == 0) ? (double)0.485f : (c == 1) ? (double)0.456f : (double)0.406f;
  const float* p = x + (size_t)bc * 65536;

  for (int i = t; i < 16384; i += 256) hist[i] = 0u;

  const int y0 = r * 64;
  qrow[y0 & 1][t] = (unsigned short)quantize_px(p[y0 * 256 + t], S, M);
  __syncthreads();

  const bool xr = t < 255;
  for (int y = y0; y < y0 + 64; ++y) {
    const int cur = y & 1, nxt = cur ^ 1;
    const bool yd = (y + 1) < 256;
    if (yd) qrow[nxt][t] = (unsigned short)quantize_px(p[(y + 1) * 256 + t], S, M);
    __syncthreads();
    const int q00 = qrow[cur][t];
    const int q01 = xr ? (int)qrow[cur][t + 1] : 0;
    if (xr) {
      int b0 = q00 * 256 + q01;
      if ((b0 >> 15) == half)
        atomicAdd(&hist[(b0 >> 1) & 16383], 1u << ((b0 & 1) * 16));
    }
    if (yd) {
      const int q10 = qrow[nxt][t];
      int b1 = q00 * 256 + q10;
      if ((b1 >> 15) == half)
        atomicAdd(&hist[(b1 >> 1) & 16383], 1u << ((b1 & 1) * 16));
      if (xr) {
        const int q11 = qrow[nxt][t + 1];
        int b2 = q00 * 256 + q11;
        int b3 = q01 * 256 + q10;
        if ((b2 >> 15) == half)
          atomicAdd(&hist[(b2 >> 1) & 16383], 1u << ((b2 & 1) * 16));
        if ((b3 >> 15) == half)
          atomicAdd(&hist[(b3 >> 1) & 16383], 1u << ((b3 & 1) * 16));
      }
    }
    __syncthreads();
  }

  unsigned int* outp = hcopy + ((size_t)r * 48 + bc) * 32768 + half * 16384;
  for (int i = t; i < 16384; i += 256) outp[i] = hist[i];
}

__global__ __launch_bounds__(256) void co_reduce(const unsigned int* __restrict__ hcopy,
                                                 float* __restrict__ co) {
  int i = blockIdx.x * 256 + threadIdx.x;     // 48*32768 words
  int bc = i >> 15, w = i & 32767;
  unsigned int lo = 0, hi = 0;
#pragma unroll
  for (int r = 0; r < 4; ++r) {
    unsigned int v = hcopy[((size_t)r * 48 + bc) * 32768 + w];
    lo += v & 0xFFFFu;
    hi += v >> 16;
  }
  float2 o;
  o.x = (float)lo;
  o.y = (float)hi;
  *(float2*)&co[(size_t)bc * 65536 + w * 2] = o;
}

// ---------------------------------------------------------------------------
// VALU conv (kept ONLY for conv1, CIN=3 — too narrow for K=32 MFMA).
// ---------------------------------------------------------------------------
template <int K, int CIN, int COUT, int H, int W, bool RELU, bool POOL>
__global__ __launch_bounds__(256, 2) void conv_fast(
    const float* __restrict__ in, const float* __restrict__ wgt,
    const float* __restrict__ bias, float* __restrict__ out) {
  constexpr int TH = 16, TW = 16, CO_BLK = 16;
  constexpr int CI_BLK = (CIN % 8 == 0) ? 8 : CIN;
  constexpr int PAD = K / 2;
  constexpr int IR = TH + K - 1, IC = TW + K - 1, ICP = IC + 1;
  constexpr int TILES_X = W / TW;

  __shared__ float s_in[CI_BLK][IR][ICP];
  __shared__ float s_w[CO_BLK][CI_BLK][K * K];

  const int t = threadIdx.x;
  const int by = blockIdx.x / TILES_X, bx = blockIdx.x % TILES_X;
  const int co_base = blockIdx.y * CO_BLK;
  const int b = blockIdx.z;

  const int cog = t >> 6;
  const int pg = t & 63;
  const int py0 = (pg >> 3) * 2;
  const int px0 = (pg & 7) * 2;

  float acc[2][2][4];
#pragma unroll
  for (int i = 0; i < 2; ++i)
#pragma unroll
    for (int j = 0; j < 2; ++j)
#pragma unroll
      for (int k = 0; k < 4; ++k) acc[i][j][k] = 0.f;

  const int y0g = by * TH - PAD, x0g = bx * TW - PAD;
  const float* inb = in + (size_t)b * CIN * H * W;

  for (int ci0 = 0; ci0 < CIN; ci0 += CI_BLK) {
    for (int i = t; i < CI_BLK * IR * IC; i += 256) {
      int ci = i / (IR * IC), rem = i % (IR * IC);
      int rr = rem / IC, cc = rem % IC;
      int gy = y0g + rr, gx = x0g + cc;
      float v = 0.f;
      if (gy >= 0 && gy < H && gx >= 0 && gx < W)
        v = tf32r(inb[(size_t)(ci0 + ci) * H * W + gy * W + gx]);
      s_in[ci][rr][cc] = v;
    }
    for (int i = t; i < CO_BLK * CI_BLK * K * K; i += 256) {
      int co = i / (CI_BLK * K * K), rem = i % (CI_BLK * K * K);
      int ci = rem / (K * K), kk = rem % (K * K);
      s_w[co][ci][kk] =
          tf32r(wgt[((size_t)(co_base + co) * CIN + (ci0 + ci)) * K * K + kk]);
    }
    __syncthreads();

#pragma unroll 1
    for (int ci = 0; ci < CI_BLK; ++ci) {
#pragma unroll
      for (int ky = 0; ky < K; ++ky) {
        float wr[4][K];
#pragma unroll
        for (int co = 0; co < 4; ++co)
#pragma unroll
          for (int kx = 0; kx < K; ++kx)
            wr[co][kx] = s_w[cog * 4 + co][ci][ky * K + kx];
#pragma unroll
        for (int py = 0; py < 2; ++py) {
          float r[K + 1];
#pragma unroll
          for (int j = 0; j < K + 1; ++j)
            r[j] = s_in[ci][py0 + py + ky][px0 + j];
#pragma unroll
          for (int kx = 0; kx < K; ++kx)
#pragma unroll
            for (int px = 0; px < 2; ++px)
#pragma unroll
              for (int co = 0; co < 4; ++co)
                acc[py][px][co] = fmaf(r[px + kx], wr[co][kx], acc[py][px][co]);
        }
      }
    }
    __syncthreads();
  }

  if (POOL) {
    constexpr int HO = H / 2, WO = W / 2;
    int oy = by * (TH / 2) + (pg >> 3), ox = bx * (TW / 2) + (pg & 7);
#pragma unroll
    for (int co = 0; co < 4; ++co) {
      int cg = co_base + cog * 4 + co;
      float v = fmaxf(fmaxf(acc[0][0][co], acc[0][1][co]),
                      fmaxf(acc[1][0][co], acc[1][1][co]));
      v += bias[cg];
      out[((size_t)b * COUT + cg) * HO * WO + oy * WO + ox] = v;
    }
  } else {
#pragma unroll
    for (int co = 0; co < 4; ++co) {
      int cg = co_base + cog * 4 + co;
      float bv = bias[cg];
#pragma unroll
      for (int py = 0; py < 2; ++py) {
        float2 v;
        v.x = acc[py][0][co] + bv;
        v.y = acc[py][1][co] + bv;
        if (RELU) { v.x = fmaxf(v.x, 0.f); v.y = fmaxf(v.y, 0.f); }
        *(float2*)&out[((size_t)b * COUT + cg) * H * W +
                       (by * TH + py0 + py) * W + (bx * TW + px0)] = v;
      }
    }
  }
}

// ---------------------------------------------------------------------------
// Weight pre-transform: f32 [CO][CI][K*K] -> bf16 hi/lo [tap][CO][CI].
// ---------------------------------------------------------------------------
__global__ void wprep(const float* __restrict__ w, unsigned short* __restrict__ whi,
                      unsigned short* __restrict__ wlo, int CO, int CI, int KK) {
  int i = blockIdx.x * 256 + threadIdx.x;
  if (i >= KK * CO * CI) return;
  int ci = i % CI;
  int rem = i / CI;
  int co = rem % CO;
  int tap = rem / CO;
  float v = w[((size_t)co * CI + ci) * KK + tap];
  unsigned short h = bf16_hi(v);
  whi[i] = h;
  wlo[i] = bf16_hi(v - bf16_f(h));
}

// ---------------------------------------------------------------------------
// MFMA conv (conv2..conv6): tap-decomposed implicit GEMM, split-bf16 f32
// emulation (acc += ahi*bhi + ahi*blo + alo*bhi; fp32 accumulate).
// R8 post-mortem: occupancy 22->44% with MfmaUtil 22->13.6% — latency-bound
// on the per-tap weight-load chain, NOT occupancy-bound. R6 geometry restored
// (bit-identical numerics, absmax 3.81e-6) + EXPLICIT next-tap weight
// register prefetch: tap t+1's 4x16B loads issue before tap t's MFMAs
// (tap 0's before the staging barrier). +16 VGPR, order-preserving.
// ---------------------------------------------------------------------------
template <int K, int CIN, int COUT, int H, int W, int WC, int WR, int XS, bool POOL>
__global__ __launch_bounds__(256, 4) void conv_mfma(
    const float* __restrict__ in, const unsigned short* __restrict__ whi,
    const unsigned short* __restrict__ wlo, const float* __restrict__ bias,
    float* __restrict__ out) {
  constexpr int XW = 4 / (WC * WR);
  static_assert(WC * WR * XW == 4, "wave decomposition");
  constexpr int RW = POOL ? 2 : 1;     // rows per wave
  constexpr int RB = WR * RW;          // rows per block
  constexpr int P = RW * XS;
  constexpr int PAD = K / 2;
  constexpr int BX = 16 * XS * XW;
  constexpr int RIN = RB + K - 1;
  constexpr int XIN = BX + K - 1;
  constexpr int CIP = 40;              // 32 ci + 8 pad -> 80B px stride
  constexpr int XT = W / BX;
  constexpr int KK = K * K;
  static_assert(CIN % 32 == 0, "ci blocking");
  static_assert(W % BX == 0, "x tiling");
  static_assert(H % RB == 0, "y tiling");

  __shared__ __align__(16) unsigned short s_hi[RIN][XIN][CIP];
  __shared__ __align__(16) unsigned short s_lo[RIN][XIN][CIP];

  const int t = threadIdx.x;
  const int l = t & 63, l15 = l & 15, cig = l >> 4;
  const int wv = t >> 6;
  const int wc = wv / (WR * XW);
  const int wrm = wv % (WR * XW);
  const int wr = wrm / XW, wx = wrm % XW;
  const int tx = blockIdx.x % XT, ty = blockIdx.x / XT;
  const int x0 = tx * BX, y0 = ty * RB;
  const int xloc = wx * 16 * XS;
  const int yloc = wr * RW;
  const int cb = blockIdx.y * (32 * WC) + wc * 32;
  const int b = blockIdx.z;

  f32x4 acc[2][P];
#pragma unroll
  for (int f = 0; f < 2; ++f)
#pragma unroll
    for (int p = 0; p < P; ++p)
#pragma unroll
      for (int k = 0; k < 4; ++k) acc[f][p][k] = 0.f;

  const float* inb = in + (size_t)b * CIN * H * W;
  const int wbase = (cb + l15) * CIN + cig * 8;   // lane's weight row offset

#pragma unroll 1
  for (int ci0 = 0; ci0 < CIN; ci0 += 32) {
    // ---- prefetch tap 0 weights (independent of LDS; hides under staging) --
    short8_t cah[2], cal[2];
#pragma unroll
    for (int f = 0; f < 2; ++f) {
      int off = wbase + (0 * COUT + f * 16) * CIN + ci0;
      cah[f] = *(const short8_t*)(whi + off);
      cal[f] = *(const short8_t*)(wlo + off);
    }

    // ---- stage 32 ci of halo'd input, f32 -> bf16 hi/lo ----
    constexpr int NIT = RIN * XIN * 8;   // 8 groups of 4 ci
    const float* cbase = inb + (size_t)ci0 * H * W;
    for (int i = t; i < NIT; i += 256) {
      int xx = i % XIN;
      int rem = i / XIN;
      int c4 = (rem & 7) * 4;
      int r = rem >> 3;
      int gy = y0 + r - PAD, gx = x0 + xx - PAD;
      float v0 = 0.f, v1 = 0.f, v2 = 0.f, v3 = 0.f;
      if (gy >= 0 && gy < H && gx >= 0 && gx < W) {
        const float* p = cbase + ((size_t)c4 * H + gy) * W + gx;
        v0 = p[0];
        v1 = p[(size_t)H * W];
        v2 = p[2 * (size_t)H * W];
        v3 = p[3 * (size_t)H * W];
      }
      unsigned short h0 = bf16_hi(v0), h1 = bf16_hi(v1);
      unsigned short h2 = bf16_hi(v2), h3 = bf16_hi(v3);
      unsigned short e0 = bf16_hi(v0 - bf16_f(h0)), e1 = bf16_hi(v1 - bf16_f(h1));
      unsigned short e2 = bf16_hi(v2 - bf16_f(h2)), e3 = bf16_hi(v3 - bf16_f(h3));
      uint2 ph, pl;
      ph.x = (unsigned)h0 | ((unsigned)h1 << 16);
      ph.y = (unsigned)h2 | ((unsigned)h3 << 16);
      pl.x = (unsigned)e0 | ((unsigned)e1 << 16);
      pl.y = (unsigned)e2 | ((unsigned)e3 << 16);
      *(uint2*)&s_hi[r][xx][c4] = ph;
      *(uint2*)&s_lo[r][xx][c4] = pl;
    }
    __syncthreads();

    // ---- tap loop with next-tap weight prefetch (order-preserving) ----
#pragma unroll
    for (int tt = 0; tt < KK; ++tt) {
      const int ky = tt / K, kx = tt % K;
      short8_t nah[2], nal[2];
      if (tt + 1 < KK) {
#pragma unroll
        for (int f = 0; f < 2; ++f) {
          int off = wbase + ((tt + 1) * COUT + f * 16) * CIN + ci0;
          nah[f] = *(const short8_t*)(whi + off);
          nal[f] = *(const short8_t*)(wlo + off);
        }
      }
#pragma unroll
      for (int fr = 0; fr < RW; ++fr) {
#pragma unroll
        for (int fx = 0; fx < XS; ++fx) {
          const int pf = fr * XS + fx;
          const int xr = xloc + fx * 16 + kx + l15;
          short8_t bh = *(const short8_t*)&s_hi[yloc + fr + ky][xr][cig * 8];
          short8_t bl = *(const short8_t*)&s_lo[yloc + fr + ky][xr][cig * 8];
#pragma unroll
          for (int f = 0; f < 2; ++f) {
            acc[f][pf] = __builtin_amdgcn_mfma_f32_16x16x32_bf16(
                cah[f], bh, acc[f][pf], 0, 0, 0);
            acc[f][pf] = __builtin_amdgcn_mfma_f32_16x16x32_bf16(
                cah[f], bl, acc[f][pf], 0, 0, 0);
            acc[f][pf] = __builtin_amdgcn_mfma_f32_16x16x32_bf16(
                cal[f], bh, acc[f][pf], 0, 0, 0);
          }
        }
      }
      if (tt + 1 < KK) {
#pragma unroll
        for (int f = 0; f < 2; ++f) { cah[f] = nah[f]; cal[f] = nal[f]; }
      }
    }
    __syncthreads();
  }

  // ---- epilogue: D lane map col(px)=l&15, row(co)=cig*4+r ----
  if (POOL) {
    constexpr int HO = H / 2, WO = W / 2;
    const int oy = (y0 + yloc) >> 1;
#pragma unroll
    for (int f = 0; f < 2; ++f)
#pragma unroll
      for (int fx = 0; fx < XS; ++fx)
#pragma unroll
        for (int r = 0; r < 4; ++r) {
          float m = fmaxf(acc[f][fx][r], acc[f][XS + fx][r]);  // row pair
          float mm = fmaxf(m, __shfl_xor(m, 1));               // x pair
          if ((l15 & 1) == 0) {
            int co = cb + f * 16 + cig * 4 + r;
            int ox = (x0 + xloc + fx * 16 + l15) >> 1;
            out[((size_t)(b * COUT + co) * HO + oy) * WO + ox] = mm + bias[co];
          }
        }
  } else {
#pragma unroll
    for (int f = 0; f < 2; ++f)
#pragma unroll
      for (int fx = 0; fx < XS; ++fx)
#pragma unroll
        for (int r = 0; r < 4; ++r) {
          int co = cb + f * 16 + cig * 4 + r;
          float v = fmaxf(acc[f][fx][r] + bias[co], 0.f);      // relu layers
          out[((size_t)(b * COUT + co) * H + y0 + yloc) * W +
              x0 + xloc + fx * 16 + l15] = v;
        }
  }
}

// ---------------------------------------------------------------------------
// FC1 as split-bf16 MFMA GEMM: [16 b x 131072] x [131072 x 256 o].
// ---------------------------------------------------------------------------
__global__ __launch_bounds__(256) void hprep(const float* __restrict__ h,
                                             unsigned short* __restrict__ hhi,
                                             unsigned short* __restrict__ hlo) {
  int i = blockIdx.x * 256 + threadIdx.x;     // 2,097,152 elements
  float v = h[i];
  unsigned short hi = bf16_hi(v);
  hhi[i] = hi;
  hlo[i] = bf16_hi(v - bf16_f(hi));
}

__global__ __launch_bounds__(256) void fc1_mfma(const float* __restrict__ w,
                                                const unsigned short* __restrict__ hhi,
                                                const unsigned short* __restrict__ hlo,
                                                float* __restrict__ partial) {
  const int t = threadIdx.x;
  const int l15 = t & 15, cig = (t >> 4) & 3, wv = t >> 6;
  const int o0 = blockIdx.x * 16;
  const int slot = blockIdx.y * 4 + wv;       // 0..255
  const int kbase = slot * 512 + cig * 8;
  const float* wrow = w + (size_t)(o0 + l15) * 131072;
  const unsigned short* hh = hhi + (size_t)l15 * 131072;
  const unsigned short* hl = hlo + (size_t)l15 * 131072;
  f32x4 acc = {0.f, 0.f, 0.f, 0.f};
#pragma unroll 4
  for (int ks = 0; ks < 16; ++ks) {
    const int k = kbase + ks * 32;
    float4 w0 = *(const float4*)(wrow + k);
    float4 w1 = *(const float4*)(wrow + k + 4);
    float wf[8] = {w0.x, w0.y, w0.z, w0.w, w1.x, w1.y, w1.z, w1.w};
    short8_t ah, al;
#pragma unroll
    for (int j = 0; j < 8; ++j) {
      unsigned short h_ = bf16_hi(wf[j]);
      ah[j] = (short)h_;
      al[j] = (short)bf16_hi(wf[j] - bf16_f(h_));
    }
    short8_t bh = *(const short8_t*)(hh + k);
    short8_t bl = *(const short8_t*)(hl + k);
    acc = __builtin_amdgcn_mfma_f32_16x16x32_bf16(ah, bh, acc, 0, 0, 0);
    acc = __builtin_amdgcn_mfma_f32_16x16x32_bf16(ah, bl, acc, 0, 0, 0);
    acc = __builtin_amdgcn_mfma_f32_16x16x32_bf16(al, bh, acc, 0, 0, 0);
  }
  // D: col = l15 = batch, row = cig*4+r = o offset. Layout [slot][b][o].
  float* pr = partial + ((size_t)slot * 16 + l15) * 256 + o0 + cig * 4;
#pragma unroll
  for (int r = 0; r < 4; ++r) pr[r] = acc[r];
}

__global__ __launch_bounds__(256) void fc1_reduce(const float* __restrict__ partial,
                                                  const float* __restrict__ fb1,
                                                  float* __restrict__ f1) {
  const int b = blockIdx.x, o = threadIdx.x;  // 16 x 256
  float s = 0.f;
#pragma unroll 8
  for (int sl = 0; sl < 256; ++sl) s += partial[((size_t)sl * 16 + b) * 256 + o];
  f1[b * 256 + o] = fmaxf(s + fb1[o], 0.f);
}

__global__ void fc2_kernel(const float* __restrict__ f1,
                           const float* __restrict__ w,
                           const float* __restrict__ fb2,
                           float* __restrict__ f2) {
  int bb = blockIdx.x, o = threadIdx.x;
  __shared__ float s[256];
  s[o] = tf32r(f1[bb * 256 + o]);
  __syncthreads();
  const float* wr = w + (size_t)o * 256;
  float acc = 0.f;
#pragma unroll 8
  for (int k = 0; k < 256; ++k) acc = fmaf(tf32r(wr[k]), s[k], acc);
  f2[bb * 256 + o] = fmaxf(acc + fb2[o], 0.f);
}

__global__ void fc3_kernel(const float* __restrict__ f2,
                           const float* __restrict__ w,
                           const float* __restrict__ fb3,
                           float* __restrict__ out) {
  int bb = blockIdx.x, t = threadIdx.x;  // 64 threads = 1 wave
  float p = 0.f;
#pragma unroll
  for (int k = t; k < 256; k += 64)
    p = fmaf(tf32r(w[k]), tf32r(f2[bb * 256 + k]), p);
#pragma unroll
  for (int off = 32; off; off >>= 1) p += __shfl_down(p, off);
  if (t == 0) {
    double z = (double)p + (double)fb3[0];
    out[bb] = (float)(1.0 / (1.0 + exp(-z)));
  }
}

// ---------------------------------------------------------------------------
extern "C" void kernel_launch(void* const* d_in, const int* in_sizes, int n_in,
                              void* d_out, int out_size, void* d_ws,
                              size_t ws_size, hipStream_t stream) {
  const float* x   = (const float*)d_in[0];
  const float* w1  = (const float*)d_in[1];  const float* b1  = (const float*)d_in[2];
  const float* w2  = (const float*)d_in[3];  const float* b2  = (const float*)d_in[4];
  const float* w3  = (const float*)d_in[5];  const float* b3  = (const float*)d_in[6];
  const float* w4  = (const float*)d_in[7];  const float* b4  = (const float*)d_in[8];
  const float* w5  = (const float*)d_in[9];  const float* b5  = (const float*)d_in[10];
  const float* w6  = (const float*)d_in[11]; const float* b6  = (const float*)d_in[12];
  const float* fw1 = (const float*)d_in[13]; const float* fb1 = (const float*)d_in[14];
  const float* fw2 = (const float*)d_in[15]; const float* fb2 = (const float*)d_in[16];
  const float* fw3 = (const float*)d_in[17]; const float* fb3 = (const float*)d_in[18];
  float* outp = (float*)d_out;

  float* big    = (float*)d_ws;                // 33,554,432 floats (134 MB)
  float* small  = big + 33554432;              //  8,388,608 floats (33.5 MB)
  float* f1     = small + 8388608;             //  4096
  float* f2     = f1 + 4096;                   //  4096
  // bf16 hi/lo weight arrays for conv2..6 (2.52 MB total), [tap][co][ci]
  unsigned short* w2h = (unsigned short*)(f2 + 4096);
  unsigned short* w2l = w2h + 25600;           // 25*32*32
  unsigned short* w3h = w2l + 25600;
  unsigned short* w3l = w3h + 18432;           // 9*64*32
  unsigned short* w4h = w3l + 18432;
  unsigned short* w4l = w4h + 102400;          // 25*64*64
  unsigned short* w5h = w4l + 102400;
  unsigned short* w5l = w5h + 73728;           // 9*128*64
  unsigned short* w6h = w5l + 73728;
  unsigned short* w6l = w6h + 409600;          // 25*128*128

  // fc1 scratch lives in `big` (free once conv6 has consumed conv5's output)
  unsigned short* hhi = (unsigned short*)big;        // 2,097,152 u16 = 4 MB
  unsigned short* hlo = hhi + 2097152;               // 4 MB
  float* partial = (float*)(hlo + 2097152);          // 256*16*256 f32 = 4 MB

  // weight pre-transform (tiny)
  wprep<<<(25600 + 255) / 256, 256, 0, stream>>>(w2, w2h, w2l, 32, 32, 25);
  wprep<<<(18432 + 255) / 256, 256, 0, stream>>>(w3, w3h, w3l, 64, 32, 9);
  wprep<<<(102400 + 255) / 256, 256, 0, stream>>>(w4, w4h, w4l, 64, 64, 25);
  wprep<<<(73728 + 255) / 256, 256, 0, stream>>>(w5, w5h, w5l, 128, 64, 9);
  wprep<<<(409600 + 255) / 256, 256, 0, stream>>>(w6, w6h, w6l, 128, 128, 25);

  // co-occurrence: LDS-private histograms -> 4 packed copies (in `big`) ->
  // reduce into `small`.
  unsigned int* hcopy = (unsigned int*)big;    // 4*48*32768 u32 = 25.2 MB
  co_hist<<<dim3(48, 4, 2), 256, 0, stream>>>(x, hcopy);
  co_reduce<<<6144, 256, 0, stream>>>(hcopy, small);

  // conv1: VALU path (CIN=3)
  conv_fast<3, 3, 32, 256, 256, true, false>
      <<<dim3(256, 2, 16), 256, 0, stream>>>(small, w1, b1, big);

  // conv2..6: MFMA split-bf16 path (R6 geometry + weight prefetch)
  conv_mfma<5, 32, 32, 256, 256, 1, 2, 1, true>
      <<<dim3(8 * 64, 1, 16), 256, 0, stream>>>(big, w2h, w2l, b2, small);
  conv_mfma<3, 32, 64, 128, 128, 2, 1, 2, false>
      <<<dim3(2 * 128, 1, 16), 256, 0, stream>>>(small, w3h, w3l, b3, big);
  conv_mfma<5, 64, 64, 128, 128, 2, 2, 2, true>
      <<<dim3(4 * 32, 1, 16), 256, 0, stream>>>(big, w4h, w4l, b4, small);
  conv_mfma<3, 64, 128, 64, 64, 2, 1, 2, false>
      <<<dim3(1 * 64, 2, 16), 256, 0, stream>>>(small, w5h, w5l, b5, big);
  conv_mfma<5, 128, 128, 64, 64, 2, 2, 2, true>
      <<<dim3(2 * 16, 2, 16), 256, 0, stream>>>(big, w6h, w6l, b6, small);

  // fc head: fc1 via MFMA (weights read exactly once), fc2/fc3 tiny
  hprep<<<8192, 256, 0, stream>>>(small, hhi, hlo);
  fc1_mfma<<<dim3(16, 64), 256, 0, stream>>>(fw1, hhi, hlo, partial);
  fc1_reduce<<<16, 256, 0, stream>>>(partial, fb1, f1);
  fc2_kernel<<<16, 256, 0, stream>>>(f1, fw2, fb2, f2);
  fc3_kernel<<<16, 64, 0, stream>>>(f2, fw3, fb3, outp);
}